// Round 7
// baseline (297.586 us; speedup 1.0000x reference)
//
#include <hip/hip_runtime.h>
#include <hip/hip_fp16.h>

#define NMESH 128
#define NMESH2 (128 * 128)
#define NMESH3 (128 * 128 * 128)
#define NPOINTS 100000
#define NCH 16

#define NBINS 4096       // 16^3 bins of 8^3 cells
#define BINW 8
#define BIN_CAP 64       // Poisson mean 24.4; P(>64) ~ 1e-15 per bin

#define HALOXY 10        // staged cells in x,y (8 + 1 halo each side)
#define ZW 16            // staged cells in z (aligned window, covers taps)
#define PITCH_US 272     // ushorts per (lx,ly) row = ZW*16 + 8 pad (544 B)

// ---------------------------------------------------------------------------
// Binning pass A: zero the per-bin counters.
// ---------------------------------------------------------------------------
__global__ __launch_bounds__(256) void bin_zero_kernel(int* __restrict__ bin_count)
{
    const int i = blockIdx.x * 256 + threadIdx.x;
    if (i < NBINS) bin_count[i] = 0;
}

// ---------------------------------------------------------------------------
// Binning pass B: scatter point indices into spatial bins (8^3 cells/bin).
// rx/ry/rz use EXACTLY the gather's expressions so binning agrees bit-for-bit.
// ---------------------------------------------------------------------------
__global__ __launch_bounds__(256) void bin_scatter_kernel(
    const float* __restrict__ pts,
    int* __restrict__ bin_count,
    int* __restrict__ sorted_p)
{
    const int p = blockIdx.x * 256 + threadIdx.x;
    if (p >= NPOINTS) return;

    const float SP = 0.1f;
    const int rxw = (int)rintf(pts[p * 3 + 0] / SP) & (NMESH - 1);
    const int ryw = (int)rintf(pts[p * 3 + 1] / SP) & (NMESH - 1);
    const int rzw = (int)rintf(pts[p * 3 + 2] / SP) & (NMESH - 1);

    const int b = ((rxw >> 3) << 8) | ((ryw >> 3) << 4) | (rzw >> 3);
    const int slot = atomicAdd(&bin_count[b], 1);
    if (slot < BIN_CAP) sorted_p[b * BIN_CAP + slot] = p;
}

// ---------------------------------------------------------------------------
// FUSED kernel: per-bin halo staging DIRECTLY from the fp32 (C,X,Y,Z) mesh
// (convert to fp16 in-register), then LDS tap loop. One block per bin.
//   stage: 3200 items = cpair(8) x lx(10) x ly(10) x zchunk(4); each item
//          reads 2x float4 (z-contiguous, 16B-aligned), packs 4x b32 LDS
//          writes into [row][z][c] tile with 544B row pitch (8-bank stagger).
//   tap  : identical math/order to previous rounds => bitwise-same output.
// ---------------------------------------------------------------------------
__global__ __launch_bounds__(512) void fused_binned_gather_kernel(
    const float* __restrict__ mesh,     // [16][2M] fp32
    const float* __restrict__ pts,      // [100000][3]
    const int* __restrict__ bin_count,
    const int* __restrict__ sorted_p,
    float4* __restrict__ out)           // [100000][4] of float4
{
    __shared__ unsigned short tile[HALOXY * HALOXY * PITCH_US];  // 54,400 B

    const int b = blockIdx.x;
    const int bx = b >> 8;
    const int by = (b >> 4) & 15;
    const int bz = b & 15;

    // ---- stage halo: z-window = cells [8*bz-4, 8*bz+12), float4-aligned ----
    uint32_t* tile32 = (uint32_t*)tile;
    for (int j = threadIdx.x; j < 8 * HALOXY * HALOXY * 4; j += 512) {
        const int zc  = j & 3;
        const int t2  = j >> 2;          // cp*100 + lx*10 + ly
        const int ly  = t2 % 10;
        const int t3  = t2 / 10;
        const int lx  = t3 % 10;
        const int cp  = t3 / 10;         // channel pair 0..7

        const int gx = (bx * BINW - 1 + lx) & (NMESH - 1);
        const int gy = (by * BINW - 1 + ly) & (NMESH - 1);
        const int gz = (bz * BINW - 4 + 4 * zc) & (NMESH - 1);
        const size_t sidx = (size_t)(gx * NMESH + gy) * NMESH + gz;

        const float4 fa = *(const float4*)(mesh + (size_t)(2 * cp + 0) * NMESH3 + sidx);
        const float4 fb = *(const float4*)(mesh + (size_t)(2 * cp + 1) * NMESH3 + sidx);

        const float fav[4] = {fa.x, fa.y, fa.z, fa.w};
        const float fbv[4] = {fb.x, fb.y, fb.z, fb.w};
        const int row = lx * 10 + ly;
#pragma unroll
        for (int jz = 0; jz < 4; ++jz) {
            const uint32_t u =
                (uint32_t)__half_as_ushort(__float2half(fav[jz])) |
                ((uint32_t)__half_as_ushort(__float2half(fbv[jz])) << 16);
            // ushort offset = row*PITCH_US + (4*zc+jz)*16 + 2*cp ; dword = /2
            tile32[row * (PITCH_US / 2) + (4 * zc + jz) * 8 + cp] = u;
        }
    }
    __syncthreads();

    // ---- tap loop (identical arithmetic to previous rounds) ----
    const int cnt = min(bin_count[b], BIN_CAP);
    const int q = threadIdx.x & 3;       // channel quad

    for (int g = threadIdx.x >> 2; g < cnt; g += 128) {
        const int p = sorted_p[b * BIN_CAP + g];

        const float SP = 0.1f;
        const float pcx = pts[p * 3 + 0] / SP;
        const float pcy = pts[p * 3 + 1] / SP;
        const float pcz = pts[p * 3 + 2] / SP;

        const int rx = (int)rintf(pcx);
        const int ry = (int)rintf(pcy);
        const int rz = (int)rintf(pcz);

        const float dx = pcx - (float)rx;
        const float dy = pcy - (float)ry;
        const float dz = pcz - (float)rz;

        float wX[3], wY[3], wZ[3];
        wX[0] = (2.0f * dx - 1.0f) * (2.0f * dx - 1.0f) * 0.125f;
        wX[1] = 0.75f - dx * dx;
        wX[2] = (2.0f * dx + 1.0f) * (2.0f * dx + 1.0f) * 0.125f;
        wY[0] = (2.0f * dy - 1.0f) * (2.0f * dy - 1.0f) * 0.125f;
        wY[1] = 0.75f - dy * dy;
        wY[2] = (2.0f * dy + 1.0f) * (2.0f * dy + 1.0f) * 0.125f;
        wZ[0] = (2.0f * dz - 1.0f) * (2.0f * dz - 1.0f) * 0.125f;
        wZ[1] = 0.75f - dz * dz;
        wZ[2] = (2.0f * dz + 1.0f) * (2.0f * dz + 1.0f) * 0.125f;

        // local staged coords
        const int lrx = (rx & (NMESH - 1)) - bx * BINW + 1;   // 1..8
        const int lry = (ry & (NMESH - 1)) - by * BINW + 1;   // 1..8
        const int lrz = (rz & (NMESH - 1)) - bz * BINW + 4;   // 4..11

        float4 acc = make_float4(0.0f, 0.0f, 0.0f, 0.0f);
#pragma unroll
        for (int a = 0; a < 3; ++a) {
#pragma unroll
            for (int bb = 0; bb < 3; ++bb) {
                const int row = (lrx - 1 + a) * 10 + (lry - 1 + bb);
                const unsigned short* base =
                    tile + row * PITCH_US + (lrz - 1) * NCH + q * 4;
                const float wxy = wX[a] * wY[bb];
#pragma unroll
                for (int k = 0; k < 3; ++k) {
                    union { uint2 u; __half2 h[2]; } d;
                    d.u = *(const uint2*)(base + k * NCH);   // +32 B per z
                    const float2 f01 = __half22float2(d.h[0]);
                    const float2 f23 = __half22float2(d.h[1]);
                    const float w = wxy * wZ[k];
                    acc.x = fmaf(f01.x, w, acc.x);
                    acc.y = fmaf(f01.y, w, acc.y);
                    acc.z = fmaf(f23.x, w, acc.z);
                    acc.w = fmaf(f23.y, w, acc.w);
                }
            }
        }
        out[p * 4 + q] = acc;
    }
}

// ---------------------------------------------------------------------------
// Fallback in case ws_size is too small for the bin arrays.
// ---------------------------------------------------------------------------
__global__ __launch_bounds__(256) void mesh_interp_fallback_kernel(
    const float* __restrict__ mesh,
    const float* __restrict__ pts,
    float* __restrict__ out)
{
    const int tid = blockIdx.x * 256 + threadIdx.x;
    const int c = tid & (NCH - 1);
    const int p = tid >> 4;
    if (p >= NPOINTS) return;

    const float SP = 0.1f;
    const float pcx = pts[p * 3 + 0] / SP;
    const float pcy = pts[p * 3 + 1] / SP;
    const float pcz = pts[p * 3 + 2] / SP;

    const int rx = (int)rintf(pcx);
    const int ry = (int)rintf(pcy);
    const int rz = (int)rintf(pcz);

    const float dx = pcx - (float)rx;
    const float dy = pcy - (float)ry;
    const float dz = pcz - (float)rz;

    float wX[3], wY[3], wZ[3];
    wX[0] = (2.0f * dx - 1.0f) * (2.0f * dx - 1.0f) * 0.125f;
    wX[1] = 0.75f - dx * dx;
    wX[2] = (2.0f * dx + 1.0f) * (2.0f * dx + 1.0f) * 0.125f;
    wY[0] = (2.0f * dy - 1.0f) * (2.0f * dy - 1.0f) * 0.125f;
    wY[1] = 0.75f - dy * dy;
    wY[2] = (2.0f * dy + 1.0f) * (2.0f * dy + 1.0f) * 0.125f;
    wZ[0] = (2.0f * dz - 1.0f) * (2.0f * dz - 1.0f) * 0.125f;
    wZ[1] = 0.75f - dz * dz;
    wZ[2] = (2.0f * dz + 1.0f) * (2.0f * dz + 1.0f) * 0.125f;

    int xb[3], yb[3], zi[3];
#pragma unroll
    for (int k = 0; k < 3; ++k) {
        xb[k] = ((rx - 1 + k) & (NMESH - 1)) * NMESH2;
        yb[k] = ((ry - 1 + k) & (NMESH - 1)) * NMESH;
        zi[k] = ((rz - 1 + k) & (NMESH - 1));
    }

    const float* __restrict__ mc = mesh + (size_t)c * NMESH3;
    float acc = 0.0f;
#pragma unroll
    for (int a = 0; a < 3; ++a) {
#pragma unroll
        for (int b = 0; b < 3; ++b) {
            const float* __restrict__ row = mc + xb[a] + yb[b];
            const float wxy = wX[a] * wY[b];
            acc = fmaf(row[zi[0]], wxy * wZ[0], acc);
            acc = fmaf(row[zi[1]], wxy * wZ[1], acc);
            acc = fmaf(row[zi[2]], wxy * wZ[2], acc);
        }
    }
    out[tid] = acc;
}

extern "C" void kernel_launch(void* const* d_in, const int* in_sizes, int n_in,
                              void* d_out, int out_size, void* d_ws, size_t ws_size,
                              hipStream_t stream) {
    const float* mesh = (const float*)d_in[0];
    const float* pts  = (const float*)d_in[1];

    const size_t count_bytes = (size_t)NBINS * sizeof(int);             // 16 KiB
    const size_t sorted_bytes = (size_t)NBINS * BIN_CAP * sizeof(int);  // 1 MiB
    const size_t needed = count_bytes + sorted_bytes;

    if (ws_size >= needed) {
        int* bin_count = (int*)d_ws;
        int* sorted_p = bin_count + NBINS;

        bin_zero_kernel<<<NBINS / 256, 256, 0, stream>>>(bin_count);
        bin_scatter_kernel<<<(NPOINTS + 255) / 256, 256, 0, stream>>>(
            pts, bin_count, sorted_p);
        fused_binned_gather_kernel<<<NBINS, 512, 0, stream>>>(
            mesh, pts, bin_count, sorted_p, (float4*)d_out);
    } else {
        const int total = NPOINTS * NCH;
        mesh_interp_fallback_kernel<<<(total + 255) / 256, 256, 0, stream>>>(
            mesh, pts, (float*)d_out);
    }
}

// Round 8
// 232.016 us; speedup vs baseline: 1.2826x; 1.2826x over previous
//
#include <hip/hip_runtime.h>
#include <hip/hip_fp16.h>

#define NMESH 128
#define NMESH2 (128 * 128)
#define NMESH3 (128 * 128 * 128)
#define NPOINTS 100000
#define NCH 16

typedef float __attribute__((ext_vector_type(4))) f32x4;
typedef unsigned int __attribute__((ext_vector_type(4))) u32x4;

// ---------------------------------------------------------------------------
// Kernel 1 (v5): transpose (C,X,Y,Z) fp32 -> (X,Y,Z,C) fp16 via LDS bounce,
// v3 structure + NONTEMPORAL global loads/stores (streaming data, zero reuse:
// keep it out of L2 to avoid write-allocate/dirty-eviction churn).
// Tile = 256 consecutive cells per block (8192 blocks x 256 threads).
// ---------------------------------------------------------------------------
__global__ __launch_bounds__(256) void transpose_to_half_v5(
    const float* __restrict__ in,   // [16][2M]
    __half* __restrict__ outT)      // [2M][16]
{
    __shared__ float lds[NCH * 256];   // 16 KB, channel-major [c][s]
    const int t = threadIdx.x;
    const int s_base = blockIdx.x * 256;
    const int f = t & 63;      // float4 index within a channel row
    const int c0 = t >> 6;     // 0..3

    // Read phase: iteration k, wave w handles channel c0 + 4k. nt loads.
#pragma unroll
    for (int k = 0; k < 4; ++k) {
        const int c = c0 + 4 * k;
        const f32x4 v = __builtin_nontemporal_load(
            (const f32x4*)(in + (size_t)c * NMESH3 + s_base + 4 * f));
        *(f32x4*)&lds[c * 256 + 4 * f] = v;   // ds_write_b128
    }
    __syncthreads();

    // Write phase: uint4 i covers cell s=i>>1, channels h..h+7 (h=(i&1)*8).
    u32x4* o = (u32x4*)(outT + (size_t)s_base * NCH);  // 512 vec4 per tile
#pragma unroll
    for (int r = 0; r < 2; ++r) {
        const int i = t + 256 * r;
        const int s = i >> 1;
        const int h = (i & 1) * 8;
        u32x4 w;
#pragma unroll
        for (int m = 0; m < 4; ++m) {
            const float f0 = lds[(h + 2 * m + 0) * 256 + s];
            const float f1 = lds[(h + 2 * m + 1) * 256 + s];
            w[m] = (uint32_t)__half_as_ushort(__float2half(f0)) |
                   ((uint32_t)__half_as_ushort(__float2half(f1)) << 16);
        }
        __builtin_nontemporal_store(w, &o[i]);
    }
}

// ---------------------------------------------------------------------------
// Kernel 2 (round-1/5 version, measured ~16 us): gather from transposed fp16
// mesh. 4 lanes per point, lane owns channel quad; 8 B dwordx2 per tap;
// coalesced float4 output store.
// ---------------------------------------------------------------------------
__global__ __launch_bounds__(256) void gather_half_quad_kernel(
    const __half* __restrict__ meshT,  // [2M][16]
    const float* __restrict__ pts,     // [100000][3]
    float4* __restrict__ out)          // [100000][4] of float4
{
    const int tid = blockIdx.x * 256 + threadIdx.x;
    const int q = tid & 3;   // channel quad
    const int p = tid >> 2;  // point
    if (p >= NPOINTS) return;

    const float SP = 0.1f;
    const float pcx = pts[p * 3 + 0] / SP;
    const float pcy = pts[p * 3 + 1] / SP;
    const float pcz = pts[p * 3 + 2] / SP;

    const int rx = (int)rintf(pcx);
    const int ry = (int)rintf(pcy);
    const int rz = (int)rintf(pcz);

    const float dx = pcx - (float)rx;
    const float dy = pcy - (float)ry;
    const float dz = pcz - (float)rz;

    float wX[3], wY[3], wZ[3];
    wX[0] = (2.0f * dx - 1.0f) * (2.0f * dx - 1.0f) * 0.125f;
    wX[1] = 0.75f - dx * dx;
    wX[2] = (2.0f * dx + 1.0f) * (2.0f * dx + 1.0f) * 0.125f;
    wY[0] = (2.0f * dy - 1.0f) * (2.0f * dy - 1.0f) * 0.125f;
    wY[1] = 0.75f - dy * dy;
    wY[2] = (2.0f * dy + 1.0f) * (2.0f * dy + 1.0f) * 0.125f;
    wZ[0] = (2.0f * dz - 1.0f) * (2.0f * dz - 1.0f) * 0.125f;
    wZ[1] = 0.75f - dz * dz;
    wZ[2] = (2.0f * dz + 1.0f) * (2.0f * dz + 1.0f) * 0.125f;

    int xo[3], yo[3], zq[3];
#pragma unroll
    for (int k = 0; k < 3; ++k) {
        xo[k] = ((rx - 1 + k) & (NMESH - 1)) * (NMESH2 * NCH);
        yo[k] = ((ry - 1 + k) & (NMESH - 1)) * (NMESH * NCH);
        zq[k] = ((rz - 1 + k) & (NMESH - 1)) * NCH + q * 4;
    }

    float4 acc = make_float4(0.0f, 0.0f, 0.0f, 0.0f);
#pragma unroll
    for (int a = 0; a < 3; ++a) {
#pragma unroll
        for (int b = 0; b < 3; ++b) {
            const __half* __restrict__ base = meshT + xo[a] + yo[b];
            const float wxy = wX[a] * wY[b];
#pragma unroll
            for (int k = 0; k < 3; ++k) {
                union { uint2 u; __half2 h[2]; } d;
                d.u = *(const uint2*)(base + zq[k]);
                const float2 f01 = __half22float2(d.h[0]);
                const float2 f23 = __half22float2(d.h[1]);
                const float w = wxy * wZ[k];
                acc.x = fmaf(f01.x, w, acc.x);
                acc.y = fmaf(f01.y, w, acc.y);
                acc.z = fmaf(f23.x, w, acc.z);
                acc.w = fmaf(f23.y, w, acc.w);
            }
        }
    }

    out[tid] = acc;
}

// ---------------------------------------------------------------------------
// Fallback in case ws_size is too small for the fp16 mesh.
// ---------------------------------------------------------------------------
__global__ __launch_bounds__(256) void mesh_interp_fallback_kernel(
    const float* __restrict__ mesh,
    const float* __restrict__ pts,
    float* __restrict__ out)
{
    const int tid = blockIdx.x * 256 + threadIdx.x;
    const int c = tid & (NCH - 1);
    const int p = tid >> 4;
    if (p >= NPOINTS) return;

    const float SP = 0.1f;
    const float pcx = pts[p * 3 + 0] / SP;
    const float pcy = pts[p * 3 + 1] / SP;
    const float pcz = pts[p * 3 + 2] / SP;

    const int rx = (int)rintf(pcx);
    const int ry = (int)rintf(pcy);
    const int rz = (int)rintf(pcz);

    const float dx = pcx - (float)rx;
    const float dy = pcy - (float)ry;
    const float dz = pcz - (float)rz;

    float wX[3], wY[3], wZ[3];
    wX[0] = (2.0f * dx - 1.0f) * (2.0f * dx - 1.0f) * 0.125f;
    wX[1] = 0.75f - dx * dx;
    wX[2] = (2.0f * dx + 1.0f) * (2.0f * dx + 1.0f) * 0.125f;
    wY[0] = (2.0f * dy - 1.0f) * (2.0f * dy - 1.0f) * 0.125f;
    wY[1] = 0.75f - dy * dy;
    wY[2] = (2.0f * dy + 1.0f) * (2.0f * dy + 1.0f) * 0.125f;
    wZ[0] = (2.0f * dz - 1.0f) * (2.0f * dz - 1.0f) * 0.125f;
    wZ[1] = 0.75f - dz * dz;
    wZ[2] = (2.0f * dz + 1.0f) * (2.0f * dz + 1.0f) * 0.125f;

    int xb[3], yb[3], zi[3];
#pragma unroll
    for (int k = 0; k < 3; ++k) {
        xb[k] = ((rx - 1 + k) & (NMESH - 1)) * NMESH2;
        yb[k] = ((ry - 1 + k) & (NMESH - 1)) * NMESH;
        zi[k] = ((rz - 1 + k) & (NMESH - 1));
    }

    const float* __restrict__ mc = mesh + (size_t)c * NMESH3;
    float acc = 0.0f;
#pragma unroll
    for (int a = 0; a < 3; ++a) {
#pragma unroll
        for (int b = 0; b < 3; ++b) {
            const float* __restrict__ row = mc + xb[a] + yb[b];
            const float wxy = wX[a] * wY[b];
            acc = fmaf(row[zi[0]], wxy * wZ[0], acc);
            acc = fmaf(row[zi[1]], wxy * wZ[1], acc);
            acc = fmaf(row[zi[2]], wxy * wZ[2], acc);
        }
    }
    out[tid] = acc;
}

extern "C" void kernel_launch(void* const* d_in, const int* in_sizes, int n_in,
                              void* d_out, int out_size, void* d_ws, size_t ws_size,
                              hipStream_t stream) {
    const float* mesh = (const float*)d_in[0];
    const float* pts  = (const float*)d_in[1];

    const size_t needed = (size_t)NMESH3 * NCH * sizeof(__half);  // 64 MiB

    if (ws_size >= needed) {
        __half* meshT = (__half*)d_ws;
        transpose_to_half_v5<<<NMESH3 / 256, 256, 0, stream>>>(mesh, meshT);
        const int total = NPOINTS * 4;  // 4 lanes per point (channel quads)
        gather_half_quad_kernel<<<(total + 255) / 256, 256, 0, stream>>>(
            meshT, pts, (float4*)d_out);
    } else {
        const int total = NPOINTS * NCH;
        mesh_interp_fallback_kernel<<<(total + 255) / 256, 256, 0, stream>>>(
            mesh, pts, (float*)d_out);
    }
}

// Round 9
// 224.638 us; speedup vs baseline: 1.3247x; 1.0328x over previous
//
#include <hip/hip_runtime.h>
#include <hip/hip_fp16.h>

#define NMESH 128
#define NMESH2 (128 * 128)
#define NMESH3 (128 * 128 * 128)
#define NPOINTS 100000
#define NCH 16

// ---------------------------------------------------------------------------
// Kernel 1 (v6): transpose (C,X,Y,Z) fp32 -> (X,Y,Z,C) fp16 via LDS bounce.
// v3 mechanics (conflict-free LDS, 1KB-contiguous stores) BUT 2 tiles per
// block with ALL 8 dwordx4 loads hoisted before any LDS write -> 128 B of
// reads in flight per thread (2x v3) to test/fix read-latency-boundedness.
// Grid 4096 blocks x 256 threads; 32 KB LDS -> 5 blocks/CU, 20 waves/CU.
// ---------------------------------------------------------------------------
__global__ __launch_bounds__(256) void transpose_to_half_v6(
    const float* __restrict__ in,   // [16][2M]
    __half* __restrict__ outT)      // [2M][16]
{
    __shared__ float lds[2][NCH * 256];   // 2 tiles x 16 KB
    const int t = threadIdx.x;
    const int s_base = blockIdx.x * 512;
    const int f = t & 63;      // float4 index within a channel row
    const int c0 = t >> 6;     // 0..3

    // ---- hoisted load phase: 8 independent dwordx4 loads, all in flight ----
    float4 v[2][4];
#pragma unroll
    for (int u = 0; u < 2; ++u) {
#pragma unroll
        for (int k = 0; k < 4; ++k) {
            const int c = c0 + 4 * k;
            v[u][k] = *(const float4*)(in + (size_t)c * NMESH3 + s_base +
                                       u * 256 + 4 * f);
        }
    }

    // ---- LDS stage (conflict-free: v3 pattern) ----
#pragma unroll
    for (int u = 0; u < 2; ++u) {
#pragma unroll
        for (int k = 0; k < 4; ++k) {
            const int c = c0 + 4 * k;
            *(float4*)&lds[u][c * 256 + 4 * f] = v[u][k];   // ds_write_b128
        }
    }
    __syncthreads();

    // ---- store phase: per tile, uint4 i covers cell s=i>>1, ch h..h+7 ----
#pragma unroll
    for (int u = 0; u < 2; ++u) {
        uint4* o = (uint4*)(outT + (size_t)(s_base + u * 256) * NCH);
#pragma unroll
        for (int r = 0; r < 2; ++r) {
            const int i = t + 256 * r;
            const int s = i >> 1;
            const int h = (i & 1) * 8;
            uint32_t w[4];
#pragma unroll
            for (int m = 0; m < 4; ++m) {
                const float f0 = lds[u][(h + 2 * m + 0) * 256 + s];
                const float f1 = lds[u][(h + 2 * m + 1) * 256 + s];
                w[m] = (uint32_t)__half_as_ushort(__float2half(f0)) |
                       ((uint32_t)__half_as_ushort(__float2half(f1)) << 16);
            }
            o[i] = make_uint4(w[0], w[1], w[2], w[3]);
        }
    }
}

// ---------------------------------------------------------------------------
// Kernel 2 (round-5 version, ~16 us measured by elimination): gather from
// transposed fp16 mesh. 4 lanes per point, lane owns channel quad; 8 B
// dwordx2 per tap; coalesced float4 output store.
// ---------------------------------------------------------------------------
__global__ __launch_bounds__(256) void gather_half_quad_kernel(
    const __half* __restrict__ meshT,  // [2M][16]
    const float* __restrict__ pts,     // [100000][3]
    float4* __restrict__ out)          // [100000][4] of float4
{
    const int tid = blockIdx.x * 256 + threadIdx.x;
    const int q = tid & 3;   // channel quad
    const int p = tid >> 2;  // point
    if (p >= NPOINTS) return;

    const float SP = 0.1f;
    const float pcx = pts[p * 3 + 0] / SP;
    const float pcy = pts[p * 3 + 1] / SP;
    const float pcz = pts[p * 3 + 2] / SP;

    const int rx = (int)rintf(pcx);
    const int ry = (int)rintf(pcy);
    const int rz = (int)rintf(pcz);

    const float dx = pcx - (float)rx;
    const float dy = pcy - (float)ry;
    const float dz = pcz - (float)rz;

    float wX[3], wY[3], wZ[3];
    wX[0] = (2.0f * dx - 1.0f) * (2.0f * dx - 1.0f) * 0.125f;
    wX[1] = 0.75f - dx * dx;
    wX[2] = (2.0f * dx + 1.0f) * (2.0f * dx + 1.0f) * 0.125f;
    wY[0] = (2.0f * dy - 1.0f) * (2.0f * dy - 1.0f) * 0.125f;
    wY[1] = 0.75f - dy * dy;
    wY[2] = (2.0f * dy + 1.0f) * (2.0f * dy + 1.0f) * 0.125f;
    wZ[0] = (2.0f * dz - 1.0f) * (2.0f * dz - 1.0f) * 0.125f;
    wZ[1] = 0.75f - dz * dz;
    wZ[2] = (2.0f * dz + 1.0f) * (2.0f * dz + 1.0f) * 0.125f;

    int xo[3], yo[3], zq[3];
#pragma unroll
    for (int k = 0; k < 3; ++k) {
        xo[k] = ((rx - 1 + k) & (NMESH - 1)) * (NMESH2 * NCH);
        yo[k] = ((ry - 1 + k) & (NMESH - 1)) * (NMESH * NCH);
        zq[k] = ((rz - 1 + k) & (NMESH - 1)) * NCH + q * 4;
    }

    float4 acc = make_float4(0.0f, 0.0f, 0.0f, 0.0f);
#pragma unroll
    for (int a = 0; a < 3; ++a) {
#pragma unroll
        for (int b = 0; b < 3; ++b) {
            const __half* __restrict__ base = meshT + xo[a] + yo[b];
            const float wxy = wX[a] * wY[b];
#pragma unroll
            for (int k = 0; k < 3; ++k) {
                union { uint2 u; __half2 h[2]; } d;
                d.u = *(const uint2*)(base + zq[k]);
                const float2 f01 = __half22float2(d.h[0]);
                const float2 f23 = __half22float2(d.h[1]);
                const float w = wxy * wZ[k];
                acc.x = fmaf(f01.x, w, acc.x);
                acc.y = fmaf(f01.y, w, acc.y);
                acc.z = fmaf(f23.x, w, acc.z);
                acc.w = fmaf(f23.y, w, acc.w);
            }
        }
    }

    out[tid] = acc;
}

// ---------------------------------------------------------------------------
// Fallback in case ws_size is too small for the fp16 mesh.
// ---------------------------------------------------------------------------
__global__ __launch_bounds__(256) void mesh_interp_fallback_kernel(
    const float* __restrict__ mesh,
    const float* __restrict__ pts,
    float* __restrict__ out)
{
    const int tid = blockIdx.x * 256 + threadIdx.x;
    const int c = tid & (NCH - 1);
    const int p = tid >> 4;
    if (p >= NPOINTS) return;

    const float SP = 0.1f;
    const float pcx = pts[p * 3 + 0] / SP;
    const float pcy = pts[p * 3 + 1] / SP;
    const float pcz = pts[p * 3 + 2] / SP;

    const int rx = (int)rintf(pcx);
    const int ry = (int)rintf(pcy);
    const int rz = (int)rintf(pcz);

    const float dx = pcx - (float)rx;
    const float dy = pcy - (float)ry;
    const float dz = pcz - (float)rz;

    float wX[3], wY[3], wZ[3];
    wX[0] = (2.0f * dx - 1.0f) * (2.0f * dx - 1.0f) * 0.125f;
    wX[1] = 0.75f - dx * dx;
    wX[2] = (2.0f * dx + 1.0f) * (2.0f * dx + 1.0f) * 0.125f;
    wY[0] = (2.0f * dy - 1.0f) * (2.0f * dy - 1.0f) * 0.125f;
    wY[1] = 0.75f - dy * dy;
    wY[2] = (2.0f * dy + 1.0f) * (2.0f * dy + 1.0f) * 0.125f;
    wZ[0] = (2.0f * dz - 1.0f) * (2.0f * dz - 1.0f) * 0.125f;
    wZ[1] = 0.75f - dz * dz;
    wZ[2] = (2.0f * dz + 1.0f) * (2.0f * dz + 1.0f) * 0.125f;

    int xb[3], yb[3], zi[3];
#pragma unroll
    for (int k = 0; k < 3; ++k) {
        xb[k] = ((rx - 1 + k) & (NMESH - 1)) * NMESH2;
        yb[k] = ((ry - 1 + k) & (NMESH - 1)) * NMESH;
        zi[k] = ((rz - 1 + k) & (NMESH - 1));
    }

    const float* __restrict__ mc = mesh + (size_t)c * NMESH3;
    float acc = 0.0f;
#pragma unroll
    for (int a = 0; a < 3; ++a) {
#pragma unroll
        for (int b = 0; b < 3; ++b) {
            const float* __restrict__ row = mc + xb[a] + yb[b];
            const float wxy = wX[a] * wY[b];
            acc = fmaf(row[zi[0]], wxy * wZ[0], acc);
            acc = fmaf(row[zi[1]], wxy * wZ[1], acc);
            acc = fmaf(row[zi[2]], wxy * wZ[2], acc);
        }
    }
    out[tid] = acc;
}

extern "C" void kernel_launch(void* const* d_in, const int* in_sizes, int n_in,
                              void* d_out, int out_size, void* d_ws, size_t ws_size,
                              hipStream_t stream) {
    const float* mesh = (const float*)d_in[0];
    const float* pts  = (const float*)d_in[1];

    const size_t needed = (size_t)NMESH3 * NCH * sizeof(__half);  // 64 MiB

    if (ws_size >= needed) {
        __half* meshT = (__half*)d_ws;
        transpose_to_half_v6<<<NMESH3 / 512, 256, 0, stream>>>(mesh, meshT);
        const int total = NPOINTS * 4;  // 4 lanes per point (channel quads)
        gather_half_quad_kernel<<<(total + 255) / 256, 256, 0, stream>>>(
            meshT, pts, (float4*)d_out);
    } else {
        const int total = NPOINTS * NCH;
        mesh_interp_fallback_kernel<<<(total + 255) / 256, 256, 0, stream>>>(
            mesh, pts, (float*)d_out);
    }
}